// Round 12
// baseline (41.292 us; speedup 1.0000x reference)
//
#include <hip/hip_runtime.h>
#include <math.h>

// Problem constants (match reference setup_inputs)
#define B 32
#define S 4096
#define E 256
#define H 256
#define T 64
#define J (T - 2)
#define NROWS (B * S)  // 131072

__device__ __forceinline__ float dot4(float4 v, float4 w) {
    return fmaf(v.x, w.x, fmaf(v.y, w.y, fmaf(v.z, w.z, v.w * w.w)));
}

// Kernel 1 (R10-proven 4-row streamer): d[row] = dot(enc[row,:], We).
// 4 independent 1KB loads in flight per wave; one float4 store; 8192 blocks.
// Block 0 also zeroes the tail's counter+accumulator (visible at node boundary).
__global__ __launch_bounds__(256) void row_dot4_kernel(
    const float* __restrict__ enc,
    const float* __restrict__ We,
    float* __restrict__ d,
    float* __restrict__ accum,
    unsigned int* __restrict__ counter) {
    const int tid  = threadIdx.x;
    const int lane = tid & 63;
    const int wv   = (blockIdx.x << 2) | (tid >> 6);  // global wave id

    if (blockIdx.x == 0 && tid == 0) { *accum = 0.0f; *counter = 0u; }

    const float4  w4 = reinterpret_cast<const float4*>(We)[lane];
    const float4* p  = reinterpret_cast<const float4*>(enc)
                     + (size_t)wv * 256 + lane;       // 4 rows x 64 float4
    float s0 = dot4(p[0],   w4);
    float s1 = dot4(p[64],  w4);
    float s2 = dot4(p[128], w4);
    float s3 = dot4(p[192], w4);
#pragma unroll
    for (int off = 32; off >= 1; off >>= 1) {
        s0 += __shfl_xor(s0, off, 64);
        s1 += __shfl_xor(s1, off, 64);
        s2 += __shfl_xor(s2, off, 64);
        s3 += __shfl_xor(s3, off, 64);
    }
    if (lane == 0)
        reinterpret_cast<float4*>(d)[wv] = make_float4(s0, s1, s2, s3);
}

// Kernel 2: one block per batch. Wave w computes segments w*16..w*16+15:
// all 16 strided 64-lane loads issued independently (registers, static
// indices), then 16 shuffle reduces -> tt[]. Thread 0 runs the validated
// suffix-LSE scan, atomicAdd's the batch loss; the LAST-arriving block
// (atomicAdd counter, old==B-1: no polling!) writes out[0].
__global__ __launch_bounds__(256) void batch_tail_kernel(
    const float* __restrict__ d,
    const int* __restrict__ ends,
    float* __restrict__ accum,
    unsigned int* __restrict__ counter,
    float* __restrict__ out) {
    const int b    = blockIdx.x;
    const int tid  = threadIdx.x;
    const int w    = tid >> 6;
    const int lane = tid & 63;

    __shared__ int   el[T];
    __shared__ float tt[T];

    if (tid < T) el[tid] = ends[b * T + tid];
    __syncthreads();

    const float* db = d + (size_t)b * S;
    float v[16];
    int   st[16], e[16];
#pragma unroll
    for (int k = 0; k < 16; ++k) {
        const int seg = w * 16 + k;
        e[k]  = el[seg];
        st[k] = (seg == 0) ? 0 : (el[seg - 1] + 1);
        const int i = st[k] + lane;
        v[k] = (i <= e[k]) ? db[i] : 0.0f;   // 16 independent loads in flight
    }
#pragma unroll
    for (int k = 0; k < 16; ++k)             // general-length tail (0 iters here)
        for (int i = st[k] + 64 + lane; i <= e[k]; i += 64) v[k] += db[i];
#pragma unroll
    for (int k = 0; k < 16; ++k) {
#pragma unroll
        for (int off = 32; off >= 1; off >>= 1)
            v[k] += __shfl_xor(v[k], off, 64);
        if (lane == 0)
            tt[w * 16 + k] = v[k] / (float)(e[k] - st[k] + 1);
    }
    __syncthreads();

    if (tid == 0) {
        // Suffix-LSE scan (validated R4/R6/R9 numerics).
        float M = tt[T - 1], a = 1.0f, ls = 0.0f;
        for (int j = J - 1; j >= 0; --j) {
            ls += logf(a) + M - tt[j + 2];
            if (j > 0) {
                const float x  = tt[j + 1];
                const float M2 = fmaxf(M, x);
                a = a * __expf(M - M2) + __expf(x - M2);
                M = M2;
            }
        }
        atomicAdd(accum, ls);                 // device-scope
        __threadfence();
        const unsigned int old = atomicAdd(counter, 1u);
        if (old == B - 1) {                   // last arrival: everyone's add done
            __threadfence();
            const float tot = __hip_atomic_load(accum, __ATOMIC_ACQUIRE,
                                                __HIP_MEMORY_SCOPE_AGENT);
            out[0] = tot / (float)(B * J);
        }
    }
}

extern "C" void kernel_launch(void* const* d_in, const int* in_sizes, int n_in,
                              void* d_out, int out_size, void* d_ws, size_t ws_size,
                              hipStream_t stream) {
    // Inputs: 0 encoder_output (B,S,E) f32; 1 his_turn_end_ids (B,T) i32;
    // 2..5 LSTM weights (algebraically dead); 6 fc_w (1,H+E); 7 fc_b (dead).
    // loss[b,j] = LSE_{m=j+2..T-1}(t[b,m]) - t[b,j+2], t = seg_mean(enc) @ We,
    // We = fc_w[0, H:]. LSTM path and fc_b cancel inside LSE - logits[...,0].
    const float* enc  = (const float*)d_in[0];
    const int*   ends = (const int*)d_in[1];
    const float* We   = (const float*)d_in[6] + H;

    float*        dbuf    = (float*)d_ws;            // NROWS floats = 512 KiB
    float*        accum   = dbuf + NROWS;
    unsigned int* counter = (unsigned int*)(accum + 1);
    float*        out     = (float*)d_out;

    row_dot4_kernel<<<NROWS / 16, 256, 0, stream>>>(enc, We, dbuf, accum, counter);
    batch_tail_kernel<<<B, 256, 0, stream>>>(dbuf, ends, accum, counter, out);
}

// Round 13
// 35.705 us; speedup vs baseline: 1.1565x; 1.1565x over previous
//
#include <hip/hip_runtime.h>
#include <math.h>

// Problem constants (match reference setup_inputs)
#define B 32
#define S 4096
#define E 256
#define H 256
#define T 64
#define J (T - 2)
#define NROWS (B * S)  // 131072

__device__ __forceinline__ float dot4(float4 v, float4 w) {
    return fmaf(v.x, w.x, fmaf(v.y, w.y, fmaf(v.z, w.z, v.w * w.w)));
}

// Kernel 1 (R10-proven best): streaming row-dot, 4 contiguous rows per wave.
// 4 independent 1KB loads in flight per wave; 4 interleaved shuffle-reduce
// chains; one float4 store; 8192 blocks. MLP-saturated (8-row gained nothing).
__global__ __launch_bounds__(256) void row_dot4_kernel(
    const float* __restrict__ enc,
    const float* __restrict__ We,
    float* __restrict__ d) {
    const int tid  = threadIdx.x;
    const int lane = tid & 63;
    const int wv   = (blockIdx.x << 2) | (tid >> 6);  // global wave id

    const float4  w4 = reinterpret_cast<const float4*>(We)[lane];
    const float4* p  = reinterpret_cast<const float4*>(enc)
                     + (size_t)wv * 256 + lane;       // 4 rows x 64 float4
    float s0 = dot4(p[0],   w4);
    float s1 = dot4(p[64],  w4);
    float s2 = dot4(p[128], w4);
    float s3 = dot4(p[192], w4);
#pragma unroll
    for (int off = 32; off >= 1; off >>= 1) {
        s0 += __shfl_xor(s0, off, 64);
        s1 += __shfl_xor(s1, off, 64);
        s2 += __shfl_xor(s2, off, 64);
        s3 += __shfl_xor(s3, off, 64);
    }
    if (lane == 0)
        reinterpret_cast<float4*>(d)[wv] = make_float4(s0, s1, s2, s3);
}

// Kernel 2 (R9/R10-proven): one 1-wave block per segment. t[g] = mean(d[seg]).
__global__ __launch_bounds__(64) void seg_mean_kernel(
    const float* __restrict__ d,
    const int* __restrict__ ends,
    float* __restrict__ t) {
    const int g    = blockIdx.x;        // b*T + tau
    const int lane = threadIdx.x;
    const int tau  = g & (T - 1);
    const int b    = g >> 6;

    const int e  = ends[g];
    const int st = (tau == 0) ? 0 : (ends[g - 1] + 1);

    const float* db = d + (size_t)b * S;
    float s = 0.0f;
    for (int i = st + lane; i <= e; i += 64) s += db[i];

#pragma unroll
    for (int off = 32; off >= 1; off >>= 1)
        s += __shfl_xor(s, off, 64);

    if (lane == 0) t[g] = s / (float)(e - st + 1);
}

// Kernel 3 (R9/R10-proven): one wave; per-batch suffix-LSE scan; mean -> out.
__global__ __launch_bounds__(64) void lse_kernel(
    const float* __restrict__ t,
    float* __restrict__ out) {
    const int lane = threadIdx.x;
    __shared__ float tl[B * T];

    const float4* tp = reinterpret_cast<const float4*>(t);
#pragma unroll
    for (int k = 0; k < 8; ++k) {
        float4 v = tp[lane + k * 64];
        const int i = 4 * (lane + k * 64);
        tl[i] = v.x; tl[i + 1] = v.y; tl[i + 2] = v.z; tl[i + 3] = v.w;
    }
    __syncthreads();

    float ls = 0.0f;
    if (lane < B) {
        const float* tb = tl + lane * T;
        float M = tb[T - 1], a = 1.0f;
        for (int j = J - 1; j >= 0; --j) {
            ls += logf(a) + M - tb[j + 2];
            if (j > 0) {
                const float x  = tb[j + 1];
                const float M2 = fmaxf(M, x);
                a = a * __expf(M - M2) + __expf(x - M2);
                M = M2;
            }
        }
    }

#pragma unroll
    for (int off = 32; off >= 1; off >>= 1)
        ls += __shfl_xor(ls, off, 64);
    if (lane == 0) out[0] = ls / (float)(B * J);
}

extern "C" void kernel_launch(void* const* d_in, const int* in_sizes, int n_in,
                              void* d_out, int out_size, void* d_ws, size_t ws_size,
                              hipStream_t stream) {
    // Inputs: 0 encoder_output (B,S,E) f32; 1 his_turn_end_ids (B,T) i32;
    // 2..5 LSTM weights (algebraically dead); 6 fc_w (1,H+E); 7 fc_b (dead).
    // loss[b,j] = LSE_{m=j+2..T-1}(t[b,m]) - t[b,j+2], t = seg_mean(enc) @ We,
    // We = fc_w[0, H:]. LSTM path and fc_b cancel inside LSE - logits[...,0].
    const float* enc  = (const float*)d_in[0];
    const int*   ends = (const int*)d_in[1];
    const float* We   = (const float*)d_in[6] + H;

    float* d   = (float*)d_ws;               // NROWS floats = 512 KiB
    float* t   = d + NROWS;                  // B*T floats
    float* out = (float*)d_out;

    row_dot4_kernel<<<NROWS / 16, 256, 0, stream>>>(enc, We, d);
    seg_mean_kernel<<<B * T, 64, 0, stream>>>(d, ends, t);
    lse_kernel<<<1, 64, 0, stream>>>(t, out);
}